// Round 11
// baseline (161.289 us; speedup 1.0000x reference)
//
#include <hip/hip_runtime.h>
#include <hip/hip_bf16.h>

#define NT   1024         // threads per block (16 waves)
#define FD   128          // feature dim
#define NPGc 32           // nodes per graph (level 0)
#define Bc   128          // graphs
#define K1c  16           // nodes per graph after pool 1
#define K2c  8            // nodes per graph after pool 2
#define EPSc 1e-5f
#define SLOPEc 0.2f

struct Params {
  const float *x;
  const float *p1_rel_w, *p1_rel_b, *p1_root_w, *p1_lin_w, *p1_lin_b,
              *p1_att_w, *p1_att_b, *p1_le1_w, *p1_le1_b, *p1_le2_w,
              *p1_le3_w, *p1_le3_b;
  const float *p2_rel_w, *p2_rel_b, *p2_root_w, *p2_lin_w, *p2_lin_b,
              *p2_att_w, *p2_att_b, *p2_le1_w, *p2_le1_b, *p2_le2_w,
              *p2_le3_w, *p2_le3_b;
  const float *c1w, *c2w, *ggw, *ggb, *gnw, *gnb;
  const int *ei;
  float *out;
  int etot;
};

// Out[ROWS][128] = A1 @ W1 (+ A2s@W2) (+ bias), W staged through LDS chunks.
// Per-thread FMA order identical to the validated round-7/9 kernel
// (k ascending, w1/w2 interleaved per k) -> bitwise-stable top-k.
// Wst: dedicated 8192-float (32KB) LDS scratch; no global loads in k-loop.
template<int ROWS, bool FUSE2>
__device__ __forceinline__ void mm128(const float* __restrict__ A1,
                                      const float* __restrict__ W1,
                                      const float* __restrict__ A2s,
                                      const float* __restrict__ W2,
                                      const float* __restrict__ bias,
                                      float* __restrict__ Out,
                                      float* __restrict__ Wst,
                                      int tid) {
  constexpr int RPG = (ROWS * FD) / NT;   // rows per 128-thread group
  constexpr int CH  = FUSE2 ? 32 : 64;    // k-rows staged per chunk
  const int fo = tid & 127;
  const int rbase = (tid >> 7) * RPG;
  float acc[RPG];
#pragma unroll
  for (int r = 0; r < RPG; ++r) acc[r] = bias ? bias[fo] : 0.f;

  for (int k0 = 0; k0 < FD; k0 += CH) {
    __syncthreads();                       // Wst safe to overwrite
    {
      const float4* s1 = reinterpret_cast<const float4*>(W1 + k0 * FD);
      float4* d1 = reinterpret_cast<float4*>(Wst);
      for (int i = tid; i < CH * FD / 4; i += NT) d1[i] = s1[i];
      if constexpr (FUSE2) {
        const float4* s2 = reinterpret_cast<const float4*>(W2 + k0 * FD);
        float4* d2 = reinterpret_cast<float4*>(Wst + CH * FD);
        for (int i = tid; i < CH * FD / 4; i += NT) d2[i] = s2[i];
      }
    }
    __syncthreads();                       // Wst ready
    const float* __restrict__ W2s = Wst + CH * FD;
    for (int kk = 0; kk < CH; kk += 4) {
      const float w10 = Wst[(kk + 0) * FD + fo];
      const float w11 = Wst[(kk + 1) * FD + fo];
      const float w12 = Wst[(kk + 2) * FD + fo];
      const float w13 = Wst[(kk + 3) * FD + fo];
      float w20, w21, w22, w23;
      if constexpr (FUSE2) {
        w20 = W2s[(kk + 0) * FD + fo];
        w21 = W2s[(kk + 1) * FD + fo];
        w22 = W2s[(kk + 2) * FD + fo];
        w23 = W2s[(kk + 3) * FD + fo];
      }
      const int k = k0 + kk;
#pragma unroll
      for (int r = 0; r < RPG; ++r) {
        const float4 a1 = *reinterpret_cast<const float4*>(&A1[(rbase + r) * FD + k]);
        float a = acc[r];
        if constexpr (FUSE2) {
          const float4 a2 = *reinterpret_cast<const float4*>(&A2s[(rbase + r) * FD + k]);
          a = fmaf(a1.x, w10, a); a = fmaf(a2.x, w20, a);
          a = fmaf(a1.y, w11, a); a = fmaf(a2.y, w21, a);
          a = fmaf(a1.z, w12, a); a = fmaf(a2.z, w22, a);
          a = fmaf(a1.w, w13, a); a = fmaf(a2.w, w23, a);
        } else {
          a = fmaf(a1.x, w10, a);
          a = fmaf(a1.y, w11, a);
          a = fmaf(a1.z, w12, a);
          a = fmaf(a1.w, w13, a);
        }
        acc[r] = a;
      }
    }
  }
#pragma unroll
  for (int r = 0; r < RPG; ++r) Out[(rbase + r) * FD + fo] = acc[r];
}

// Instance-norm + ReLU over ROWS x 128 in Hs (in place); wave-parallel.
template<int ROWS, bool WRITE_R2>
__device__ __forceinline__ void instnorm(float* __restrict__ Hs,
                                         float* __restrict__ meanB,
                                         float* __restrict__ rstdB,
                                         float* __restrict__ outMean,
                                         float* __restrict__ outMax,
                                         int tid) {
  constexpr int RPL = ROWS / 4;           // rows per lane (4 lanes per col)
  const int col = tid >> 2, ln = tid & 3;
  if (tid < 512) {
    float s = 0.f;
#pragma unroll
    for (int j = 0; j < RPL; ++j) s += Hs[(ln * RPL + j) * FD + col];
    s += __shfl_xor(s, 1); s += __shfl_xor(s, 2);
    if (ln == 0) meanB[col] = s * (1.f / ROWS);
  }
  __syncthreads();
  if (tid < 512) {
    const float mean = meanB[col];
    float v = 0.f;
#pragma unroll
    for (int j = 0; j < RPL; ++j) {
      float d = Hs[(ln * RPL + j) * FD + col] - mean;
      v += d * d;
    }
    v += __shfl_xor(v, 1); v += __shfl_xor(v, 2);
    if (ln == 0) rstdB[col] = 1.f / sqrtf(v * (1.f / ROWS) + EPSc);
  }
  __syncthreads();
  for (int idx = tid; idx < ROWS * FD; idx += NT) {
    const int c = idx & 127;
    float v = (Hs[idx] - meanB[c]) * rstdB[c];
    Hs[idx] = v > 0.f ? v : 0.f;
  }
  __syncthreads();
  if (WRITE_R2 && tid < 512) {
    float s = 0.f, m = -1e30f;
#pragma unroll
    for (int j = 0; j < RPL; ++j) {
      float v = Hs[(ln * RPL + j) * FD + col];
      s += v; m = fmaxf(m, v);
    }
    s += __shfl_xor(s, 1); s += __shfl_xor(s, 2);
    m = fmaxf(m, __shfl_xor(m, 1)); m = fmaxf(m, __shfl_xor(m, 2));
    if (ln == 0) { outMean[col] = s * (1.f / ROWS); outMax[col] = m; }
  }
}

__global__ __launch_bounds__(NT)
void mol_kernel(Params p) {
  const int g = blockIdx.x;
  const int tid = threadIdx.x;

  __shared__ float sx [NPGc * FD];
  __shared__ float bufA[NPGc * FD];
  __shared__ float xp [NPGc * FD];
  __shared__ float xq [NPGc * FD];
  __shared__ float xcb[NPGc * FD];
  __shared__ float Wst[64 * FD];      // 32KB W staging scratch
  __shared__ float Am [NPGc * NPGc];
  __shared__ float Sm [NPGc * NPGc];
  __shared__ float Mm [NPGc * K1c];   // A@Ssel / instnorm stats / pooled
  __shared__ float Hh [K1c * FD];
  __shared__ float X1 [K1c * FD];
  __shared__ float A2m[K1c * K1c];
  __shared__ float fitS[NPGc];
  __shared__ float degI[NPGc];
  __shared__ float dqS[NPGc], dpS[NPGc];
  __shared__ float sA[NPGc], sB[NPGc], sC[NPGc];
  __shared__ int   selS[NPGc];
  __shared__ float gateS[K2c];

  float* Tb  = bufA;
  float* T2b = bufA + K1c * FD;
  float* ag2 = xp;
  float* xp2 = xp + K1c * FD;
  float* xq2 = xq;
  float* xc2 = xq + K1c * FD;
  float* S2m = xcb;
  float* A3m = xcb + 256;
  float* h2b = xcb + 512;
  float* x2b = xcb + 1536;
  float* meanB = Mm;          // [128]
  float* rstdB = Mm + 256;    // [128]
  float* partial = bufA;      // [8*128] final-matmul partials

  {
    const float4* xs = reinterpret_cast<const float4*>(p.x + (size_t)g * NPGc * FD);
    float4* sd = reinterpret_cast<float4*>(sx);
    for (int i = tid; i < NPGc * FD / 4; i += NT) sd[i] = xs[i];
  }
  for (int i = tid; i < NPGc * NPGc; i += NT) Am[i] = 0.f;
  __syncthreads();

  // ---- r1: mean @ +384, max @ +512 ----
  if (tid < FD) {
    float s = 0.f, m = -1e30f;
    for (int i = 0; i < NPGc; ++i) { float v = sx[i * FD + tid]; s += v; m = fmaxf(m, v); }
    p.out[g * 640 + 384 + tid] = s * (1.f / NPGc);
    p.out[g * 640 + 512 + tid] = m;
  }

  // ---- dense multiplicity matrix ----
  for (int e = tid; e < p.etot; e += NT) {
    int s = p.ei[e];
    if ((s >> 5) == g) {
      int d = p.ei[p.etot + e] & 31;
      atomicAdd(&Am[(s & 31) * NPGc + d], 1.f);
    }
  }
  if (tid < NPGc) atomicAdd(&Am[tid * NPGc + tid], 1.f);
  __syncthreads();

  if (tid < NPGc) {
    float s = 0.f;
    for (int i = 0; i < NPGc; ++i) s += Am[i * NPGc + tid];
    degI[tid] = s;
  }
  for (int idx = tid; idx < NPGc * FD; idx += NT) {
    int d = idx >> 7, f = idx & 127;
    float s = 0.f;
    for (int i = 0; i < NPGc; ++i) s += Am[i * NPGc + d] * sx[i * FD + f];
    bufA[idx] = s;
  }
  __syncthreads();

  mm128<NPGc, true>(bufA, p.p1_rel_w, sx, p.p1_root_w, p.p1_rel_b, xp, Wst, tid);
  __syncthreads();

  for (int idx = tid; idx < NPGc * FD; idx += NT) {
    int d = idx >> 7, f = idx & 127;
    float m = -1e30f;
    for (int i = 0; i < NPGc; ++i)
      if (Am[i * NPGc + d] > 0.f) m = fmaxf(m, xp[i * FD + f]);
    xcb[idx] = m;
  }
  __syncthreads();
  mm128<NPGc, false>(xcb, p.p1_lin_w, nullptr, nullptr, p.p1_lin_b, xq, Wst, tid);
  __syncthreads();

  // ---- attention dots: 64 rows x 16 lanes ----
  {
    const int row = tid >> 4, sub = tid & 15;
    const float* v = (row < NPGc) ? (xq + row * FD) : (xp + (row - NPGc) * FD);
    const float* w = (row < NPGc) ? p.p1_att_w : (p.p1_att_w + FD);
    const float4* v4 = reinterpret_cast<const float4*>(v);
    const float4* w4 = reinterpret_cast<const float4*>(w);
    float s = 0.f;
#pragma unroll
    for (int j = 0; j < 2; ++j) {
      float4 a = v4[sub * 2 + j];
      float4 b = w4[sub * 2 + j];
      s += a.x * b.x + a.y * b.y + a.z * b.z + a.w * b.w;
    }
    s += __shfl_xor(s, 1); s += __shfl_xor(s, 2);
    s += __shfl_xor(s, 4); s += __shfl_xor(s, 8);
    if (sub == 0) { if (row < NPGc) dqS[row] = s; else dpS[row - NPGc] = s; }
  }
  __syncthreads();

  // ---- L1 masked mult-weighted softmax: 32 cols x 32 lanes ----
  {
    const int d = tid >> 5, s2 = tid & 31;
    const float ab = p.p1_att_b[0];
    const float mult = Am[s2 * NPGc + d];
    float l = dqS[d] + dpS[s2] + ab;
    l = (l > 0.f) ? l : SLOPEc * l;
    float m = (mult > 0.f) ? l : -1e30f;
#pragma unroll
    for (int m2 = 1; m2 < 32; m2 <<= 1) m = fmaxf(m, __shfl_xor(m, m2));
    float v = (mult > 0.f) ? mult * expf(l - m) : 0.f;
    float den = v;
#pragma unroll
    for (int m2 = 1; m2 < 32; m2 <<= 1) den += __shfl_xor(den, m2);
    Sm[s2 * NPGc + d] = v / den;
  }
  __syncthreads();

  for (int idx = tid; idx < NPGc * FD; idx += NT) {
    int d = idx >> 7, f = idx & 127;
    float s = 0.f;
    for (int i = 0; i < NPGc; ++i) s += Sm[i * NPGc + d] * sx[i * FD + f];
    xcb[idx] = s;
  }
  __syncthreads();

  // ---- fitness dots: 32 rows x 32 lanes ----
  {
    const int row = tid >> 5, sub = tid & 31;
    float4 xv = reinterpret_cast<const float4*>(xcb + row * FD)[sub];
    float4 wa = reinterpret_cast<const float4*>(p.p1_le1_w)[sub];
    float4 wb = reinterpret_cast<const float4*>(p.p1_le2_w)[sub];
    float4 wc = reinterpret_cast<const float4*>(p.p1_le3_w)[sub];
    float a = xv.x * wa.x + xv.y * wa.y + xv.z * wa.z + xv.w * wa.w;
    float b = xv.x * wb.x + xv.y * wb.y + xv.z * wb.z + xv.w * wb.w;
    float c = xv.x * wc.x + xv.y * wc.y + xv.z * wc.z + xv.w * wc.w;
#pragma unroll
    for (int m2 = 1; m2 < 32; m2 <<= 1) {
      a += __shfl_xor(a, m2); b += __shfl_xor(b, m2); c += __shfl_xor(c, m2);
    }
    if (sub == 0) { sA[row] = a + p.p1_le1_b[0]; sB[row] = b; sC[row] = c; }
  }
  __syncthreads();
  // ---- fitness apply: 32 cols x 32 lanes ----
  {
    const int d = tid >> 5, i = tid & 31;
    float s = Am[i * NPGc + d] * sA[i];
#pragma unroll
    for (int m2 = 1; m2 < 32; m2 <<= 1) s += __shfl_xor(s, m2);
    if (i == 0) {
      float fv = s - degI[d] * sB[d] + sC[d] + p.p1_le3_b[0];
      fitS[d] = 1.f / (1.f + expf(-fv));
    }
  }
  __syncthreads();

  if (tid < NPGc) {
    float fi = fitS[tid]; int r = 0;
    for (int j = 0; j < NPGc; ++j) { float fj = fitS[j]; r += (fj > fi) || (fj == fi && j < tid); }
    if (r < K1c) selS[r] = tid;
  }
  __syncthreads();

  for (int idx = tid; idx < K1c * FD; idx += NT) {
    int r = idx >> 7, f = idx & 127;
    int n = selS[r] & 31;
    Hh[idx] = xcb[n * FD + f] * fitS[n];
    X1[idx] = sx[n * FD + f];
  }
  __syncthreads();

  for (int idx = tid; idx < NPGc * K1c; idx += NT) {
    int i = idx >> 4, c = idx & 15;
    float s = 0.f; int sc = selS[c] & 31;
    for (int j = 0; j < NPGc; ++j) s += Am[i * NPGc + j] * Sm[j * NPGc + sc];
    Mm[idx] = s;
  }
  __syncthreads();
  for (int idx = tid; idx < K1c * K1c; idx += NT) {
    int r = idx >> 4, c = idx & 15;
    float s = 0.f; int sr = selS[r] & 31;
    for (int i = 0; i < NPGc; ++i) s += Sm[i * NPGc + sr] * Mm[i * K1c + c];
    A2m[idx] = (r == c || s != 0.f) ? 1.f : 0.f;
  }
  __syncthreads();

  // ---- GCN2 conv1 ----
  if (tid < K1c) {
    float s = 0.f;
    for (int i = 0; i < K1c; ++i) s += A2m[i * K1c + tid];
    dqS[tid] = 1.f / sqrtf(s);
  }
  __syncthreads();
  for (int idx = tid; idx < K1c * FD; idx += NT) {
    int j = idx >> 7, f = idx & 127;
    float s = 0.f;
    for (int i = 0; i < K1c; ++i) s += dqS[i] * A2m[i * K1c + j] * Hh[i * FD + f];
    Tb[idx] = 0.8f * dqS[j] * s + 0.2f * X1[idx];
  }
  __syncthreads();
  mm128<K1c, false>(Tb, p.c1w, nullptr, nullptr, nullptr, Hh, Wst, tid);
  __syncthreads();
  instnorm<K1c, true>(Hh, meanB, rstdB,
                      p.out + g * 640 + 128, p.out + g * 640 + 256, tid);
  __syncthreads();

  // ---- level 2 ----
  for (int idx = tid; idx < K1c * FD; idx += NT) {
    int j = idx >> 7, f = idx & 127;
    float s = 0.f;
    for (int i = 0; i < K1c; ++i) s += A2m[i * K1c + j] * Hh[i * FD + f];
    ag2[idx] = s;
  }
  __syncthreads();
  mm128<K1c, true>(ag2, p.p2_rel_w, Hh, p.p2_root_w, p.p2_rel_b, xp2, Wst, tid);
  __syncthreads();
  for (int idx = tid; idx < K1c * FD; idx += NT) {
    int j = idx >> 7, f = idx & 127;
    float m = -1e30f;
    for (int i = 0; i < K1c; ++i)
      if (A2m[i * K1c + j] > 0.f) m = fmaxf(m, xp2[i * FD + f]);
    Tb[idx] = m;
  }
  __syncthreads();
  mm128<K1c, false>(Tb, p.p2_lin_w, nullptr, nullptr, p.p2_lin_b, xq2, Wst, tid);
  __syncthreads();

  // ---- L2 attention dots: 32 rows x 32 lanes ----
  {
    const int row = tid >> 5, sub = tid & 31;
    const float* v = (row < K1c) ? (xq2 + row * FD) : (xp2 + (row - K1c) * FD);
    const float* w = (row < K1c) ? p.p2_att_w : (p.p2_att_w + FD);
    float4 a = reinterpret_cast<const float4*>(v)[sub];
    float4 b = reinterpret_cast<const float4*>(w)[sub];
    float s = a.x * b.x + a.y * b.y + a.z * b.z + a.w * b.w;
#pragma unroll
    for (int m2 = 1; m2 < 32; m2 <<= 1) s += __shfl_xor(s, m2);
    if (sub == 0) { if (row < K1c) dqS[row] = s; else dpS[row - K1c] = s; }
  }
  __syncthreads();

  // ---- L2 masked softmax: 16 cols x 16 lanes ----
  if (tid < K1c * K1c) {
    const int j = tid >> 4, i = tid & 15;
    const float ab = p.p2_att_b[0];
    const float av = A2m[i * K1c + j];
    float l = dpS[i] + dqS[j] + ab;
    l = (l > 0.f) ? l : SLOPEc * l;
    float m = (av > 0.f) ? l : -1e30f;
#pragma unroll
    for (int m2 = 1; m2 < 16; m2 <<= 1) m = fmaxf(m, __shfl_xor(m, m2));
    float v = (av > 0.f) ? expf(l - m) : 0.f;
    float den = v;
#pragma unroll
    for (int m2 = 1; m2 < 16; m2 <<= 1) den += __shfl_xor(den, m2);
    S2m[i * K1c + j] = v / den;
  }
  __syncthreads();
  for (int idx = tid; idx < K1c * FD; idx += NT) {
    int j = idx >> 7, f = idx & 127;
    float s = 0.f;
    for (int i = 0; i < K1c; ++i) s += S2m[i * K1c + j] * Hh[i * FD + f];
    xc2[idx] = s;
  }
  __syncthreads();

  // ---- L2 fitness dots: 16 rows x 64 lanes ----
  {
    const int row = tid >> 6, sub = tid & 63;
    float2 xv = reinterpret_cast<const float2*>(xc2 + row * FD)[sub];
    float2 wa = reinterpret_cast<const float2*>(p.p2_le1_w)[sub];
    float2 wb = reinterpret_cast<const float2*>(p.p2_le2_w)[sub];
    float2 wc = reinterpret_cast<const float2*>(p.p2_le3_w)[sub];
    float a = xv.x * wa.x + xv.y * wa.y;
    float b = xv.x * wb.x + xv.y * wb.y;
    float c = xv.x * wc.x + xv.y * wc.y;
#pragma unroll
    for (int m2 = 1; m2 < 64; m2 <<= 1) {
      a += __shfl_xor(a, m2); b += __shfl_xor(b, m2); c += __shfl_xor(c, m2);
    }
    if (sub == 0) { sA[row] = a + p.p2_le1_b[0]; sB[row] = b; sC[row] = c; }
  }
  __syncthreads();
  // ---- L2 fitness apply: 16 cols x 16 lanes ----
  if (tid < K1c * K1c) {
    const int j = tid >> 4, i = tid & 15;
    float av = A2m[i * K1c + j];
    float s = av * sA[i];
    float deg = av;
#pragma unroll
    for (int m2 = 1; m2 < 16; m2 <<= 1) {
      s += __shfl_xor(s, m2); deg += __shfl_xor(deg, m2);
    }
    if (i == 0) {
      float fv = s - deg * sB[j] + sC[j] + p.p2_le3_b[0];
      fitS[j] = 1.f / (1.f + expf(-fv));
    }
  }
  __syncthreads();
  if (tid < K1c) {
    float fi = fitS[tid]; int r = 0;
    for (int j = 0; j < K1c; ++j) { float fj = fitS[j]; r += (fj > fi) || (fj == fi && j < tid); }
    if (r < K2c) selS[r] = tid;
  }
  __syncthreads();
  for (int idx = tid; idx < K2c * FD; idx += NT) {
    int r = idx >> 7, f = idx & 127;
    int n = selS[r] & 15;
    h2b[idx] = xc2[n * FD + f] * fitS[n];
    x2b[idx] = X1[n * FD + f];
  }
  for (int idx = tid; idx < K1c * K2c; idx += NT) {
    int i = idx >> 3, c = idx & 7;
    float s = 0.f; int sc = selS[c] & 15;
    for (int j = 0; j < K1c; ++j) s += A2m[i * K1c + j] * S2m[j * K1c + sc];
    Mm[idx] = s;
  }
  __syncthreads();
  for (int idx = tid; idx < K2c * K2c; idx += NT) {
    int r = idx >> 3, c = idx & 7;
    float s = 0.f; int sr = selS[r] & 15;
    for (int i = 0; i < K1c; ++i) s += S2m[i * K1c + sr] * Mm[i * K2c + c];
    A3m[idx] = (r == c || s != 0.f) ? 1.f : 0.f;
  }
  __syncthreads();

  // ---- GCN2 conv2 ----
  if (tid < K2c) {
    float s = 0.f;
    for (int i = 0; i < K2c; ++i) s += A3m[i * K2c + tid];
    dqS[tid] = 1.f / sqrtf(s);
  }
  __syncthreads();
  for (int idx = tid; idx < K2c * FD; idx += NT) {
    int j = idx >> 7, f = idx & 127;
    float s = 0.f;
    for (int i = 0; i < K2c; ++i) s += dqS[i] * A3m[i * K2c + j] * h2b[i * FD + f];
    T2b[idx] = 0.8f * dqS[j] * s + 0.2f * x2b[idx];
  }
  __syncthreads();
  mm128<K2c, false>(T2b, p.c2w, nullptr, nullptr, nullptr, h2b, Wst, tid);
  __syncthreads();
  instnorm<K2c, false>(h2b, meanB, rstdB, nullptr, nullptr, tid);
  __syncthreads();

  // ---- gate dots: 8 rows x 64 lanes ----
  {
    const int row = tid >> 6, sub = tid & 63;
    if (row < K2c) {
      const float2 a = reinterpret_cast<const float2*>(h2b + row * FD)[sub];
      const float2 wv = reinterpret_cast<const float2*>(p.ggw)[sub];
      float s = a.x * wv.x + a.y * wv.y;
#pragma unroll
      for (int m2 = 1; m2 < 64; m2 <<= 1) s += __shfl_xor(s, m2);
      if (sub == 0) gateS[row] = s + p.ggb[0];
    }
  }
  __syncthreads();
  if (tid < K2c) {
    float m = -1e30f;
    for (int i = 0; i < K2c; ++i) m = fmaxf(m, gateS[i]);
    float e = expf(gateS[tid] - m);
    float ssum = 0.f;
    for (int i = 0; i < K2c; ++i) ssum += expf(gateS[i] - m);
    sA[tid] = e / ssum;
  }
  __syncthreads();
  if (tid < FD) {
    float s = 0.f;
    for (int r = 0; r < K2c; ++r) s += sA[r] * h2b[r * FD + tid];
    Mm[tid] = s;                    // pooled
  }
  __syncthreads();
  // ---- mol = pooled @ ga_nn_w + ga_nn_b : 8 k-groups x 128 fo ----
  {
    const int grp = tid >> 7, fo = tid & 127;
    float s = 0.f;
    for (int kk = 0; kk < 16; ++kk) {
      const int k = grp * 16 + kk;
      s = fmaf(Mm[k], p.gnw[k * FD + fo], s);
    }
    partial[grp * FD + fo] = s;
  }
  __syncthreads();
  if (tid < FD) {
    float s = p.gnb[tid];
#pragma unroll
    for (int grp = 0; grp < 8; ++grp) s += partial[grp * FD + tid];
    p.out[g * 640 + tid] = s;
  }
}

extern "C" void kernel_launch(void* const* d_in, const int* in_sizes, int n_in,
                              void* d_out, int out_size, void* d_ws, size_t ws_size,
                              hipStream_t stream) {
  (void)n_in; (void)d_ws; (void)ws_size; (void)out_size;
  Params p;
  p.x         = (const float*)d_in[0];
  p.p1_rel_w  = (const float*)d_in[1];
  p.p1_rel_b  = (const float*)d_in[2];
  p.p1_root_w = (const float*)d_in[3];
  p.p1_lin_w  = (const float*)d_in[4];
  p.p1_lin_b  = (const float*)d_in[5];
  p.p1_att_w  = (const float*)d_in[6];
  p.p1_att_b  = (const float*)d_in[7];
  p.p1_le1_w  = (const float*)d_in[8];
  p.p1_le1_b  = (const float*)d_in[9];
  p.p1_le2_w  = (const float*)d_in[10];
  p.p1_le3_w  = (const float*)d_in[11];
  p.p1_le3_b  = (const float*)d_in[12];
  p.p2_rel_w  = (const float*)d_in[13];
  p.p2_rel_b  = (const float*)d_in[14];
  p.p2_root_w = (const float*)d_in[15];
  p.p2_lin_w  = (const float*)d_in[16];
  p.p2_lin_b  = (const float*)d_in[17];
  p.p2_att_w  = (const float*)d_in[18];
  p.p2_att_b  = (const float*)d_in[19];
  p.p2_le1_w  = (const float*)d_in[20];
  p.p2_le1_b  = (const float*)d_in[21];
  p.p2_le2_w  = (const float*)d_in[22];
  p.p2_le3_w  = (const float*)d_in[23];
  p.p2_le3_b  = (const float*)d_in[24];
  p.c1w       = (const float*)d_in[25];
  p.c2w       = (const float*)d_in[26];
  p.ggw       = (const float*)d_in[27];
  p.ggb       = (const float*)d_in[28];
  p.gnw       = (const float*)d_in[29];
  p.gnb       = (const float*)d_in[30];
  p.ei        = (const int*)d_in[31];
  p.out       = (float*)d_out;
  p.etot      = in_sizes[31] / 2;
  mol_kernel<<<dim3(Bc), dim3(NT), 0, stream>>>(p);
}

// Round 12
// 82.213 us; speedup vs baseline: 1.9618x; 1.9618x over previous
//
#include <hip/hip_runtime.h>
#include <hip/hip_bf16.h>

#define NT   1024         // threads per block (16 waves)
#define FD   128          // feature dim
#define NPGc 32           // nodes per graph (level 0)
#define Bc   128          // graphs
#define K1c  16           // nodes per graph after pool 1
#define K2c  8            // nodes per graph after pool 2
#define EPSc 1e-5f
#define SLOPEc 0.2f

struct Params {
  const float *x;
  const float *p1_rel_w, *p1_rel_b, *p1_root_w, *p1_lin_w, *p1_lin_b,
              *p1_att_w, *p1_att_b, *p1_le1_w, *p1_le1_b, *p1_le2_w,
              *p1_le3_w, *p1_le3_b;
  const float *p2_rel_w, *p2_rel_b, *p2_root_w, *p2_lin_w, *p2_lin_b,
              *p2_att_w, *p2_att_b, *p2_le1_w, *p2_le1_b, *p2_le2_w,
              *p2_le3_w, *p2_le3_b;
  const float *c1w, *c2w, *ggw, *ggb, *gnw, *gnb;
  const int *ei;
  float *out;
  int etot;
};

// Out[ROWS][128] = A1 @ W1 (+ A2s@W2) (+ bias).  EXACT round-9 version:
// plain per-k cached global W loads (L2/L3 broadcast across all 128 blocks),
// float4 LDS A-reads, NO unroll pragma, NO staging.  Rounds 8/10/11 proved
// every deviation from this load stream regresses (cache-thrash signature:
// FETCH_SIZE inflation).  Per-thread FMA order validated since round 7.
template<int ROWS, bool FUSE2>
__device__ __forceinline__ void mm128(const float* __restrict__ A1,
                                      const float* __restrict__ W1,
                                      const float* __restrict__ A2s,
                                      const float* __restrict__ W2,
                                      const float* __restrict__ bias,
                                      float* __restrict__ Out, int tid) {
  constexpr int RPG = (ROWS * FD) / NT;   // rows per 128-thread group
  const int fo = tid & 127;
  const int rbase = (tid >> 7) * RPG;
  float acc[RPG];
#pragma unroll
  for (int r = 0; r < RPG; ++r) acc[r] = bias ? bias[fo] : 0.f;
  for (int k = 0; k < FD; k += 4) {
    const float w10 = W1[(k + 0) * FD + fo];
    const float w11 = W1[(k + 1) * FD + fo];
    const float w12 = W1[(k + 2) * FD + fo];
    const float w13 = W1[(k + 3) * FD + fo];
    float w20, w21, w22, w23;
    if constexpr (FUSE2) {
      w20 = W2[(k + 0) * FD + fo];
      w21 = W2[(k + 1) * FD + fo];
      w22 = W2[(k + 2) * FD + fo];
      w23 = W2[(k + 3) * FD + fo];
    }
#pragma unroll
    for (int r = 0; r < RPG; ++r) {
      const float4 a1 = *reinterpret_cast<const float4*>(&A1[(rbase + r) * FD + k]);
      float a = acc[r];
      if constexpr (FUSE2) {
        const float4 a2 = *reinterpret_cast<const float4*>(&A2s[(rbase + r) * FD + k]);
        a = fmaf(a1.x, w10, a); a = fmaf(a2.x, w20, a);
        a = fmaf(a1.y, w11, a); a = fmaf(a2.y, w21, a);
        a = fmaf(a1.z, w12, a); a = fmaf(a2.z, w22, a);
        a = fmaf(a1.w, w13, a); a = fmaf(a2.w, w23, a);
      } else {
        a = fmaf(a1.x, w10, a);
        a = fmaf(a1.y, w11, a);
        a = fmaf(a1.z, w12, a);
        a = fmaf(a1.w, w13, a);
      }
      acc[r] = a;
    }
  }
#pragma unroll
  for (int r = 0; r < RPG; ++r) Out[(rbase + r) * FD + fo] = acc[r];
}

// Instance-norm + ReLU over ROWS x 128 in Hs (in place); wave-parallel.
template<int ROWS, bool WRITE_R2>
__device__ __forceinline__ void instnorm(float* __restrict__ Hs,
                                         float* __restrict__ meanB,
                                         float* __restrict__ rstdB,
                                         float* __restrict__ outMean,
                                         float* __restrict__ outMax,
                                         int tid) {
  constexpr int RPL = ROWS / 4;           // rows per lane (4 lanes per col)
  const int col = tid >> 2, ln = tid & 3;
  if (tid < 512) {
    float s = 0.f;
#pragma unroll
    for (int j = 0; j < RPL; ++j) s += Hs[(ln * RPL + j) * FD + col];
    s += __shfl_xor(s, 1); s += __shfl_xor(s, 2);
    if (ln == 0) meanB[col] = s * (1.f / ROWS);
  }
  __syncthreads();
  if (tid < 512) {
    const float mean = meanB[col];
    float v = 0.f;
#pragma unroll
    for (int j = 0; j < RPL; ++j) {
      float d = Hs[(ln * RPL + j) * FD + col] - mean;
      v += d * d;
    }
    v += __shfl_xor(v, 1); v += __shfl_xor(v, 2);
    if (ln == 0) rstdB[col] = 1.f / sqrtf(v * (1.f / ROWS) + EPSc);
  }
  __syncthreads();
  for (int idx = tid; idx < ROWS * FD; idx += NT) {
    const int c = idx & 127;
    float v = (Hs[idx] - meanB[c]) * rstdB[c];
    Hs[idx] = v > 0.f ? v : 0.f;
  }
  __syncthreads();
  if (WRITE_R2 && tid < 512) {
    float s = 0.f, m = -1e30f;
#pragma unroll
    for (int j = 0; j < RPL; ++j) {
      float v = Hs[(ln * RPL + j) * FD + col];
      s += v; m = fmaxf(m, v);
    }
    s += __shfl_xor(s, 1); s += __shfl_xor(s, 2);
    m = fmaxf(m, __shfl_xor(m, 1)); m = fmaxf(m, __shfl_xor(m, 2));
    if (ln == 0) { outMean[col] = s * (1.f / ROWS); outMax[col] = m; }
  }
}

__global__ __launch_bounds__(NT)
void mol_kernel(Params p) {
  const int g = blockIdx.x;
  const int tid = threadIdx.x;

  __shared__ float sx [NPGc * FD];
  __shared__ float bufA[NPGc * FD];
  __shared__ float xp [NPGc * FD];
  __shared__ float xq [NPGc * FD];
  __shared__ float xcb[NPGc * FD];
  __shared__ float Am [NPGc * NPGc];
  __shared__ float Sm [NPGc * NPGc];
  __shared__ float Mm [NPGc * K1c];   // A@Ssel / instnorm stats / pooled
  __shared__ float Hh [K1c * FD];
  __shared__ float X1 [K1c * FD];
  __shared__ float A2m[K1c * K1c];
  __shared__ float fitS[NPGc];
  __shared__ float degI[NPGc];
  __shared__ float dqS[NPGc], dpS[NPGc];
  __shared__ float sA[NPGc], sB[NPGc], sC[NPGc];
  __shared__ int   selS[NPGc];
  __shared__ float gateS[K2c];

  float* Tb  = bufA;
  float* T2b = bufA + K1c * FD;
  float* ag2 = xp;
  float* xp2 = xp + K1c * FD;
  float* xq2 = xq;
  float* xc2 = xq + K1c * FD;
  float* S2m = xcb;
  float* A3m = xcb + 256;
  float* h2b = xcb + 512;
  float* x2b = xcb + 1536;
  float* meanB = Mm;          // [128]
  float* rstdB = Mm + 256;    // [128]
  float* partial = bufA;      // [8*128] final-matmul partials

  {
    const float4* xs = reinterpret_cast<const float4*>(p.x + (size_t)g * NPGc * FD);
    float4* sd = reinterpret_cast<float4*>(sx);
    for (int i = tid; i < NPGc * FD / 4; i += NT) sd[i] = xs[i];
  }
  for (int i = tid; i < NPGc * NPGc; i += NT) Am[i] = 0.f;
  __syncthreads();

  // ---- r1: mean @ +384, max @ +512 ----
  if (tid < FD) {
    float s = 0.f, m = -1e30f;
    for (int i = 0; i < NPGc; ++i) { float v = sx[i * FD + tid]; s += v; m = fmaxf(m, v); }
    p.out[g * 640 + 384 + tid] = s * (1.f / NPGc);
    p.out[g * 640 + 512 + tid] = m;
  }

  // ---- dense multiplicity matrix ----
  for (int e = tid; e < p.etot; e += NT) {
    int s = p.ei[e];
    if ((s >> 5) == g) {
      int d = p.ei[p.etot + e] & 31;
      atomicAdd(&Am[(s & 31) * NPGc + d], 1.f);
    }
  }
  if (tid < NPGc) atomicAdd(&Am[tid * NPGc + tid], 1.f);
  __syncthreads();

  if (tid < NPGc) {
    float s = 0.f;
    for (int i = 0; i < NPGc; ++i) s += Am[i * NPGc + tid];
    degI[tid] = s;
  }
  for (int idx = tid; idx < NPGc * FD; idx += NT) {
    int d = idx >> 7, f = idx & 127;
    float s = 0.f;
    for (int i = 0; i < NPGc; ++i) s += Am[i * NPGc + d] * sx[i * FD + f];
    bufA[idx] = s;
  }
  __syncthreads();

  mm128<NPGc, true>(bufA, p.p1_rel_w, sx, p.p1_root_w, p.p1_rel_b, xp, tid);
  __syncthreads();

  for (int idx = tid; idx < NPGc * FD; idx += NT) {
    int d = idx >> 7, f = idx & 127;
    float m = -1e30f;
    for (int i = 0; i < NPGc; ++i)
      if (Am[i * NPGc + d] > 0.f) m = fmaxf(m, xp[i * FD + f]);
    xcb[idx] = m;
  }
  __syncthreads();
  mm128<NPGc, false>(xcb, p.p1_lin_w, nullptr, nullptr, p.p1_lin_b, xq, tid);
  __syncthreads();

  // ---- attention dots: 64 rows x 16 lanes ----
  {
    const int row = tid >> 4, sub = tid & 15;
    const float* v = (row < NPGc) ? (xq + row * FD) : (xp + (row - NPGc) * FD);
    const float* w = (row < NPGc) ? p.p1_att_w : (p.p1_att_w + FD);
    const float4* v4 = reinterpret_cast<const float4*>(v);
    const float4* w4 = reinterpret_cast<const float4*>(w);
    float s = 0.f;
#pragma unroll
    for (int j = 0; j < 2; ++j) {
      float4 a = v4[sub * 2 + j];
      float4 b = w4[sub * 2 + j];
      s += a.x * b.x + a.y * b.y + a.z * b.z + a.w * b.w;
    }
    s += __shfl_xor(s, 1); s += __shfl_xor(s, 2);
    s += __shfl_xor(s, 4); s += __shfl_xor(s, 8);
    if (sub == 0) { if (row < NPGc) dqS[row] = s; else dpS[row - NPGc] = s; }
  }
  __syncthreads();

  // ---- L1 masked mult-weighted softmax: 32 cols x 32 lanes ----
  {
    const int d = tid >> 5, s2 = tid & 31;
    const float ab = p.p1_att_b[0];
    const float mult = Am[s2 * NPGc + d];
    float l = dqS[d] + dpS[s2] + ab;
    l = (l > 0.f) ? l : SLOPEc * l;
    float m = (mult > 0.f) ? l : -1e30f;
#pragma unroll
    for (int m2 = 1; m2 < 32; m2 <<= 1) m = fmaxf(m, __shfl_xor(m, m2));
    float v = (mult > 0.f) ? mult * expf(l - m) : 0.f;
    float den = v;
#pragma unroll
    for (int m2 = 1; m2 < 32; m2 <<= 1) den += __shfl_xor(den, m2);
    Sm[s2 * NPGc + d] = v / den;
  }
  __syncthreads();

  for (int idx = tid; idx < NPGc * FD; idx += NT) {
    int d = idx >> 7, f = idx & 127;
    float s = 0.f;
    for (int i = 0; i < NPGc; ++i) s += Sm[i * NPGc + d] * sx[i * FD + f];
    xcb[idx] = s;
  }
  __syncthreads();

  // ---- fitness dots: 32 rows x 32 lanes ----
  {
    const int row = tid >> 5, sub = tid & 31;
    float4 xv = reinterpret_cast<const float4*>(xcb + row * FD)[sub];
    float4 wa = reinterpret_cast<const float4*>(p.p1_le1_w)[sub];
    float4 wb = reinterpret_cast<const float4*>(p.p1_le2_w)[sub];
    float4 wc = reinterpret_cast<const float4*>(p.p1_le3_w)[sub];
    float a = xv.x * wa.x + xv.y * wa.y + xv.z * wa.z + xv.w * wa.w;
    float b = xv.x * wb.x + xv.y * wb.y + xv.z * wb.z + xv.w * wb.w;
    float c = xv.x * wc.x + xv.y * wc.y + xv.z * wc.z + xv.w * wc.w;
#pragma unroll
    for (int m2 = 1; m2 < 32; m2 <<= 1) {
      a += __shfl_xor(a, m2); b += __shfl_xor(b, m2); c += __shfl_xor(c, m2);
    }
    if (sub == 0) { sA[row] = a + p.p1_le1_b[0]; sB[row] = b; sC[row] = c; }
  }
  __syncthreads();
  // ---- fitness apply: 32 cols x 32 lanes ----
  {
    const int d = tid >> 5, i = tid & 31;
    float s = Am[i * NPGc + d] * sA[i];
#pragma unroll
    for (int m2 = 1; m2 < 32; m2 <<= 1) s += __shfl_xor(s, m2);
    if (i == 0) {
      float fv = s - degI[d] * sB[d] + sC[d] + p.p1_le3_b[0];
      fitS[d] = 1.f / (1.f + expf(-fv));
    }
  }
  __syncthreads();

  if (tid < NPGc) {
    float fi = fitS[tid]; int r = 0;
    for (int j = 0; j < NPGc; ++j) { float fj = fitS[j]; r += (fj > fi) || (fj == fi && j < tid); }
    if (r < K1c) selS[r] = tid;
  }
  __syncthreads();

  for (int idx = tid; idx < K1c * FD; idx += NT) {
    int r = idx >> 7, f = idx & 127;
    int n = selS[r] & 31;
    Hh[idx] = xcb[n * FD + f] * fitS[n];
    X1[idx] = sx[n * FD + f];
  }
  __syncthreads();

  for (int idx = tid; idx < NPGc * K1c; idx += NT) {
    int i = idx >> 4, c = idx & 15;
    float s = 0.f; int sc = selS[c] & 31;
    for (int j = 0; j < NPGc; ++j) s += Am[i * NPGc + j] * Sm[j * NPGc + sc];
    Mm[idx] = s;
  }
  __syncthreads();
  for (int idx = tid; idx < K1c * K1c; idx += NT) {
    int r = idx >> 4, c = idx & 15;
    float s = 0.f; int sr = selS[r] & 31;
    for (int i = 0; i < NPGc; ++i) s += Sm[i * NPGc + sr] * Mm[i * K1c + c];
    A2m[idx] = (r == c || s != 0.f) ? 1.f : 0.f;
  }
  __syncthreads();

  // ---- GCN2 conv1 ----
  if (tid < K1c) {
    float s = 0.f;
    for (int i = 0; i < K1c; ++i) s += A2m[i * K1c + tid];
    dqS[tid] = 1.f / sqrtf(s);
  }
  __syncthreads();
  for (int idx = tid; idx < K1c * FD; idx += NT) {
    int j = idx >> 7, f = idx & 127;
    float s = 0.f;
    for (int i = 0; i < K1c; ++i) s += dqS[i] * A2m[i * K1c + j] * Hh[i * FD + f];
    Tb[idx] = 0.8f * dqS[j] * s + 0.2f * X1[idx];
  }
  __syncthreads();
  mm128<K1c, false>(Tb, p.c1w, nullptr, nullptr, nullptr, Hh, tid);
  __syncthreads();
  instnorm<K1c, true>(Hh, meanB, rstdB,
                      p.out + g * 640 + 128, p.out + g * 640 + 256, tid);
  __syncthreads();

  // ---- level 2 ----
  for (int idx = tid; idx < K1c * FD; idx += NT) {
    int j = idx >> 7, f = idx & 127;
    float s = 0.f;
    for (int i = 0; i < K1c; ++i) s += A2m[i * K1c + j] * Hh[i * FD + f];
    ag2[idx] = s;
  }
  __syncthreads();
  mm128<K1c, true>(ag2, p.p2_rel_w, Hh, p.p2_root_w, p.p2_rel_b, xp2, tid);
  __syncthreads();
  for (int idx = tid; idx < K1c * FD; idx += NT) {
    int j = idx >> 7, f = idx & 127;
    float m = -1e30f;
    for (int i = 0; i < K1c; ++i)
      if (A2m[i * K1c + j] > 0.f) m = fmaxf(m, xp2[i * FD + f]);
    Tb[idx] = m;
  }
  __syncthreads();
  mm128<K1c, false>(Tb, p.p2_lin_w, nullptr, nullptr, p.p2_lin_b, xq2, tid);
  __syncthreads();

  // ---- L2 attention dots: 32 rows x 32 lanes ----
  {
    const int row = tid >> 5, sub = tid & 31;
    const float* v = (row < K1c) ? (xq2 + row * FD) : (xp2 + (row - K1c) * FD);
    const float* w = (row < K1c) ? p.p2_att_w : (p.p2_att_w + FD);
    float4 a = reinterpret_cast<const float4*>(v)[sub];
    float4 b = reinterpret_cast<const float4*>(w)[sub];
    float s = a.x * b.x + a.y * b.y + a.z * b.z + a.w * b.w;
#pragma unroll
    for (int m2 = 1; m2 < 32; m2 <<= 1) s += __shfl_xor(s, m2);
    if (sub == 0) { if (row < K1c) dqS[row] = s; else dpS[row - K1c] = s; }
  }
  __syncthreads();

  // ---- L2 masked softmax: 16 cols x 16 lanes ----
  if (tid < K1c * K1c) {
    const int j = tid >> 4, i = tid & 15;
    const float ab = p.p2_att_b[0];
    const float av = A2m[i * K1c + j];
    float l = dpS[i] + dqS[j] + ab;
    l = (l > 0.f) ? l : SLOPEc * l;
    float m = (av > 0.f) ? l : -1e30f;
#pragma unroll
    for (int m2 = 1; m2 < 16; m2 <<= 1) m = fmaxf(m, __shfl_xor(m, m2));
    float v = (av > 0.f) ? expf(l - m) : 0.f;
    float den = v;
#pragma unroll
    for (int m2 = 1; m2 < 16; m2 <<= 1) den += __shfl_xor(den, m2);
    S2m[i * K1c + j] = v / den;
  }
  __syncthreads();
  for (int idx = tid; idx < K1c * FD; idx += NT) {
    int j = idx >> 7, f = idx & 127;
    float s = 0.f;
    for (int i = 0; i < K1c; ++i) s += S2m[i * K1c + j] * Hh[i * FD + f];
    xc2[idx] = s;
  }
  __syncthreads();

  // ---- L2 fitness dots: 16 rows x 64 lanes ----
  {
    const int row = tid >> 6, sub = tid & 63;
    float2 xv = reinterpret_cast<const float2*>(xc2 + row * FD)[sub];
    float2 wa = reinterpret_cast<const float2*>(p.p2_le1_w)[sub];
    float2 wb = reinterpret_cast<const float2*>(p.p2_le2_w)[sub];
    float2 wc = reinterpret_cast<const float2*>(p.p2_le3_w)[sub];
    float a = xv.x * wa.x + xv.y * wa.y;
    float b = xv.x * wb.x + xv.y * wb.y;
    float c = xv.x * wc.x + xv.y * wc.y;
#pragma unroll
    for (int m2 = 1; m2 < 64; m2 <<= 1) {
      a += __shfl_xor(a, m2); b += __shfl_xor(b, m2); c += __shfl_xor(c, m2);
    }
    if (sub == 0) { sA[row] = a + p.p2_le1_b[0]; sB[row] = b; sC[row] = c; }
  }
  __syncthreads();
  // ---- L2 fitness apply: 16 cols x 16 lanes ----
  if (tid < K1c * K1c) {
    const int j = tid >> 4, i = tid & 15;
    float av = A2m[i * K1c + j];
    float s = av * sA[i];
    float deg = av;
#pragma unroll
    for (int m2 = 1; m2 < 16; m2 <<= 1) {
      s += __shfl_xor(s, m2); deg += __shfl_xor(deg, m2);
    }
    if (i == 0) {
      float fv = s - deg * sB[j] + sC[j] + p.p2_le3_b[0];
      fitS[j] = 1.f / (1.f + expf(-fv));
    }
  }
  __syncthreads();
  if (tid < K1c) {
    float fi = fitS[tid]; int r = 0;
    for (int j = 0; j < K1c; ++j) { float fj = fitS[j]; r += (fj > fi) || (fj == fi && j < tid); }
    if (r < K2c) selS[r] = tid;
  }
  __syncthreads();
  for (int idx = tid; idx < K2c * FD; idx += NT) {
    int r = idx >> 7, f = idx & 127;
    int n = selS[r] & 15;
    h2b[idx] = xc2[n * FD + f] * fitS[n];
    x2b[idx] = X1[n * FD + f];
  }
  for (int idx = tid; idx < K1c * K2c; idx += NT) {
    int i = idx >> 3, c = idx & 7;
    float s = 0.f; int sc = selS[c] & 15;
    for (int j = 0; j < K1c; ++j) s += A2m[i * K1c + j] * S2m[j * K1c + sc];
    Mm[idx] = s;
  }
  __syncthreads();
  for (int idx = tid; idx < K2c * K2c; idx += NT) {
    int r = idx >> 3, c = idx & 7;
    float s = 0.f; int sr = selS[r] & 15;
    for (int i = 0; i < K1c; ++i) s += S2m[i * K1c + sr] * Mm[i * K2c + c];
    A3m[idx] = (r == c || s != 0.f) ? 1.f : 0.f;
  }
  __syncthreads();

  // ---- GCN2 conv2 ----
  if (tid < K2c) {
    float s = 0.f;
    for (int i = 0; i < K2c; ++i) s += A3m[i * K2c + tid];
    dqS[tid] = 1.f / sqrtf(s);
  }
  __syncthreads();
  for (int idx = tid; idx < K2c * FD; idx += NT) {
    int j = idx >> 7, f = idx & 127;
    float s = 0.f;
    for (int i = 0; i < K2c; ++i) s += dqS[i] * A3m[i * K2c + j] * h2b[i * FD + f];
    T2b[idx] = 0.8f * dqS[j] * s + 0.2f * x2b[idx];
  }
  __syncthreads();
  mm128<K2c, false>(T2b, p.c2w, nullptr, nullptr, nullptr, h2b, tid);
  __syncthreads();
  instnorm<K2c, false>(h2b, meanB, rstdB, nullptr, nullptr, tid);
  __syncthreads();

  // ---- gate dots: 8 rows x 64 lanes ----
  {
    const int row = tid >> 6, sub = tid & 63;
    if (row < K2c) {
      const float2 a = reinterpret_cast<const float2*>(h2b + row * FD)[sub];
      const float2 wv = reinterpret_cast<const float2*>(p.ggw)[sub];
      float s = a.x * wv.x + a.y * wv.y;
#pragma unroll
      for (int m2 = 1; m2 < 64; m2 <<= 1) s += __shfl_xor(s, m2);
      if (sub == 0) gateS[row] = s + p.ggb[0];
    }
  }
  __syncthreads();
  if (tid < K2c) {
    float m = -1e30f;
    for (int i = 0; i < K2c; ++i) m = fmaxf(m, gateS[i]);
    float e = expf(gateS[tid] - m);
    float ssum = 0.f;
    for (int i = 0; i < K2c; ++i) ssum += expf(gateS[i] - m);
    sA[tid] = e / ssum;
  }
  __syncthreads();
  if (tid < FD) {
    float s = 0.f;
    for (int r = 0; r < K2c; ++r) s += sA[r] * h2b[r * FD + tid];
    Mm[tid] = s;                    // pooled
  }
  __syncthreads();
  // ---- mol = pooled @ ga_nn_w + ga_nn_b : 8 k-groups x 128 fo ----
  {
    const int grp = tid >> 7, fo = tid & 127;
    float s = 0.f;
    for (int kk = 0; kk < 16; ++kk) {
      const int k = grp * 16 + kk;
      s = fmaf(Mm[k], p.gnw[k * FD + fo], s);
    }
    partial[grp * FD + fo] = s;
  }
  __syncthreads();
  if (tid < FD) {
    float s = p.gnb[tid];
#pragma unroll
    for (int grp = 0; grp < 8; ++grp) s += partial[grp * FD + tid];
    p.out[g * 640 + tid] = s;
  }
}

extern "C" void kernel_launch(void* const* d_in, const int* in_sizes, int n_in,
                              void* d_out, int out_size, void* d_ws, size_t ws_size,
                              hipStream_t stream) {
  (void)n_in; (void)d_ws; (void)ws_size; (void)out_size;
  Params p;
  p.x         = (const float*)d_in[0];
  p.p1_rel_w  = (const float*)d_in[1];
  p.p1_rel_b  = (const float*)d_in[2];
  p.p1_root_w = (const float*)d_in[3];
  p.p1_lin_w  = (const float*)d_in[4];
  p.p1_lin_b  = (const float*)d_in[5];
  p.p1_att_w  = (const float*)d_in[6];
  p.p1_att_b  = (const float*)d_in[7];
  p.p1_le1_w  = (const float*)d_in[8];
  p.p1_le1_b  = (const float*)d_in[9];
  p.p1_le2_w  = (const float*)d_in[10];
  p.p1_le3_w  = (const float*)d_in[11];
  p.p1_le3_b  = (const float*)d_in[12];
  p.p2_rel_w  = (const float*)d_in[13];
  p.p2_rel_b  = (const float*)d_in[14];
  p.p2_root_w = (const float*)d_in[15];
  p.p2_lin_w  = (const float*)d_in[16];
  p.p2_lin_b  = (const float*)d_in[17];
  p.p2_att_w  = (const float*)d_in[18];
  p.p2_att_b  = (const float*)d_in[19];
  p.p2_le1_w  = (const float*)d_in[20];
  p.p2_le1_b  = (const float*)d_in[21];
  p.p2_le2_w  = (const float*)d_in[22];
  p.p2_le3_w  = (const float*)d_in[23];
  p.p2_le3_b  = (const float*)d_in[24];
  p.c1w       = (const float*)d_in[25];
  p.c2w       = (const float*)d_in[26];
  p.ggw       = (const float*)d_in[27];
  p.ggb       = (const float*)d_in[28];
  p.gnw       = (const float*)d_in[29];
  p.gnb       = (const float*)d_in[30];
  p.ei        = (const int*)d_in[31];
  p.out       = (float*)d_out;
  p.etot      = in_sizes[31] / 2;
  mol_kernel<<<dim3(Bc), dim3(NT), 0, stream>>>(p);
}

// Round 13
// 69.254 us; speedup vs baseline: 2.3289x; 1.1871x over previous
//
#include <hip/hip_runtime.h>
#include <hip/hip_bf16.h>

#define NT   1024         // threads per block (16 waves)
#define FD   128          // feature dim
#define NPGc 32           // nodes per graph (level 0)
#define Bc   128          // graphs
#define K1c  16           // nodes per graph after pool 1
#define K2c  8            // nodes per graph after pool 2
#define EPSc 1e-5f
#define SLOPEc 0.2f

struct Params {
  const float *x;
  const float *p1_rel_w, *p1_rel_b, *p1_root_w, *p1_lin_w, *p1_lin_b,
              *p1_att_w, *p1_att_b, *p1_le1_w, *p1_le1_b, *p1_le2_w,
              *p1_le3_w, *p1_le3_b;
  const float *p2_rel_w, *p2_rel_b, *p2_root_w, *p2_lin_w, *p2_lin_b,
              *p2_att_w, *p2_att_b, *p2_le1_w, *p2_le1_b, *p2_le2_w,
              *p2_le3_w, *p2_le3_b;
  const float *c1w, *c2w, *ggw, *ggb, *gnw, *gnb;
  const int *ei;
  float *out;
  int etot;
};

// Out[ROWS][128] = A1 @ W1 (+ A2s@W2) (+ bias).  EXACT round-9/12 version:
// plain per-k cached global W loads (L2/L3 broadcast shared by all blocks).
// Rounds 8/10/11: ANY deviation from this load stream thrashes the cache
// (FETCH_SIZE inflation signature).  Do not restructure.
template<int ROWS, bool FUSE2>
__device__ __forceinline__ void mm128(const float* __restrict__ A1,
                                      const float* __restrict__ W1,
                                      const float* __restrict__ A2s,
                                      const float* __restrict__ W2,
                                      const float* __restrict__ bias,
                                      float* __restrict__ Out, int tid) {
  constexpr int RPG = (ROWS * FD) / NT;
  const int fo = tid & 127;
  const int rbase = (tid >> 7) * RPG;
  float acc[RPG];
#pragma unroll
  for (int r = 0; r < RPG; ++r) acc[r] = bias ? bias[fo] : 0.f;
  for (int k = 0; k < FD; k += 4) {
    const float w10 = W1[(k + 0) * FD + fo];
    const float w11 = W1[(k + 1) * FD + fo];
    const float w12 = W1[(k + 2) * FD + fo];
    const float w13 = W1[(k + 3) * FD + fo];
    float w20, w21, w22, w23;
    if constexpr (FUSE2) {
      w20 = W2[(k + 0) * FD + fo];
      w21 = W2[(k + 1) * FD + fo];
      w22 = W2[(k + 2) * FD + fo];
      w23 = W2[(k + 3) * FD + fo];
    }
#pragma unroll
    for (int r = 0; r < RPG; ++r) {
      const float4 a1 = *reinterpret_cast<const float4*>(&A1[(rbase + r) * FD + k]);
      float a = acc[r];
      if constexpr (FUSE2) {
        const float4 a2 = *reinterpret_cast<const float4*>(&A2s[(rbase + r) * FD + k]);
        a = fmaf(a1.x, w10, a); a = fmaf(a2.x, w20, a);
        a = fmaf(a1.y, w11, a); a = fmaf(a2.y, w21, a);
        a = fmaf(a1.z, w12, a); a = fmaf(a2.z, w22, a);
        a = fmaf(a1.w, w13, a); a = fmaf(a2.w, w23, a);
      } else {
        a = fmaf(a1.x, w10, a);
        a = fmaf(a1.y, w11, a);
        a = fmaf(a1.z, w12, a);
        a = fmaf(a1.w, w13, a);
      }
      acc[r] = a;
    }
  }
#pragma unroll
  for (int r = 0; r < RPG; ++r) Out[(rbase + r) * FD + fo] = acc[r];
}

// Instance-norm + ReLU over ROWS x 128 in Hs (in place); wave-parallel.
template<int ROWS, bool WRITE_R2>
__device__ __forceinline__ void instnorm(float* __restrict__ Hs,
                                         float* __restrict__ meanB,
                                         float* __restrict__ rstdB,
                                         float* __restrict__ outMean,
                                         float* __restrict__ outMax,
                                         int tid) {
  constexpr int RPL = ROWS / 4;
  const int col = tid >> 2, ln = tid & 3;
  if (tid < 512) {
    float s = 0.f;
#pragma unroll
    for (int j = 0; j < RPL; ++j) s += Hs[(ln * RPL + j) * FD + col];
    s += __shfl_xor(s, 1); s += __shfl_xor(s, 2);
    if (ln == 0) meanB[col] = s * (1.f / ROWS);
  }
  __syncthreads();
  if (tid < 512) {
    const float mean = meanB[col];
    float v = 0.f;
#pragma unroll
    for (int j = 0; j < RPL; ++j) {
      float d = Hs[(ln * RPL + j) * FD + col] - mean;
      v += d * d;
    }
    v += __shfl_xor(v, 1); v += __shfl_xor(v, 2);
    if (ln == 0) rstdB[col] = 1.f / sqrtf(v * (1.f / ROWS) + EPSc);
  }
  __syncthreads();
  for (int idx = tid; idx < ROWS * FD; idx += NT) {
    const int c = idx & 127;
    float v = (Hs[idx] - meanB[c]) * rstdB[c];
    Hs[idx] = v > 0.f ? v : 0.f;
  }
  __syncthreads();
  if (WRITE_R2 && tid < 512) {
    float s = 0.f, m = -1e30f;
#pragma unroll
    for (int j = 0; j < RPL; ++j) {
      float v = Hs[(ln * RPL + j) * FD + col];
      s += v; m = fmaxf(m, v);
    }
    s += __shfl_xor(s, 1); s += __shfl_xor(s, 2);
    m = fmaxf(m, __shfl_xor(m, 1)); m = fmaxf(m, __shfl_xor(m, 2));
    if (ln == 0) { outMean[col] = s * (1.f / ROWS); outMax[col] = m; }
  }
}

__global__ __launch_bounds__(NT)
void mol_kernel(Params p) {
  const int g = blockIdx.x;
  const int tid = threadIdx.x;

  __shared__ float sx [NPGc * FD];
  __shared__ float bufA[NPGc * FD];   // agg / Tb / xc2 / T2b / partial
  __shared__ float xp [NPGc * FD];    // x_pool; later ag2/xp2
  __shared__ float xcb[NPGc * FD];    // xc; later S2m/A3m/h2b/x2b
  __shared__ float Am [NPGc * NPGc];
  __shared__ float Sm [NPGc * NPGc];
  __shared__ float Mm [NPGc * K1c];   // A@Ssel / instnorm stats / pooled
  __shared__ float Hh [K1c * FD];
  __shared__ float X1 [K1c * FD];
  __shared__ float A2m[K1c * K1c];
  __shared__ float w1pS[FD], w2pS[FD];  // lin_w @ att_w[:C] folded vectors
  __shared__ float wcS[2];              // lin_b . att_w[:C] constants
  __shared__ float fitS[NPGc];
  __shared__ float degI[NPGc];
  __shared__ float dqS[NPGc], dpS[NPGc];
  __shared__ float sA[NPGc], sB[NPGc], sC[NPGc];
  __shared__ int   selS[NPGc];
  __shared__ float gateS[K2c];

  float* Tb  = bufA;                 // [K1c*FD] conv1 temp
  float* xc2 = bufA;                 // [K1c*FD/?]: L2 cluster features (Tb dead)
  float* T2b = bufA + K1c * FD;      // [K2c*FD] conv2 temp
  float* ag2 = xp;
  float* xp2 = xp + K1c * FD;
  float* S2m = xcb;
  float* A3m = xcb + 256;
  float* h2b = xcb + 512;
  float* x2b = xcb + 1536;
  float* meanB = Mm;
  float* rstdB = Mm + 256;
  float* partial = bufA;             // [8*128] final-matmul partials

  {
    const float4* xs = reinterpret_cast<const float4*>(p.x + (size_t)g * NPGc * FD);
    float4* sd = reinterpret_cast<float4*>(sx);
    for (int i = tid; i < NPGc * FD / 4; i += NT) sd[i] = xs[i];
  }
  for (int i = tid; i < NPGc * NPGc; i += NT) Am[i] = 0.f;
  __syncthreads();

  // ---- r1: mean @ +384, max @ +512 ----
  if (tid < FD) {
    float s = 0.f, m = -1e30f;
    for (int i = 0; i < NPGc; ++i) { float v = sx[i * FD + tid]; s += v; m = fmaxf(m, v); }
    p.out[g * 640 + 384 + tid] = s * (1.f / NPGc);
    p.out[g * 640 + 512 + tid] = m;
  }

  // ---- folded attention vectors: w1p = p1_lin_w @ aw1, w2p = p2_lin_w @ aw2
  //      (x_q enters the model ONLY via x_q . att_w[:C], so the lin matmuls
  //       collapse to these 128-vectors; removes 2 of 6 big matmuls)
  {
    const int r = tid >> 3, sub = tid & 7;      // 128 rows x 8 lanes
    const float4* aw1 = reinterpret_cast<const float4*>(p.p1_att_w);
    const float4* aw2 = reinterpret_cast<const float4*>(p.p2_att_w);
    const float4* l1 = reinterpret_cast<const float4*>(p.p1_lin_w + r * FD);
    const float4* l2 = reinterpret_cast<const float4*>(p.p2_lin_w + r * FD);
    float s1 = 0.f, s2 = 0.f;
#pragma unroll
    for (int t = 0; t < 4; ++t) {
      const int j = sub * 4 + t;
      float4 a = l1[j], b = aw1[j];
      s1 += a.x * b.x + a.y * b.y + a.z * b.z + a.w * b.w;
      float4 c = l2[j], d = aw2[j];
      s2 += c.x * d.x + c.y * d.y + c.z * d.z + c.w * d.w;
    }
    s1 += __shfl_xor(s1, 1); s1 += __shfl_xor(s1, 2); s1 += __shfl_xor(s1, 4);
    s2 += __shfl_xor(s2, 1); s2 += __shfl_xor(s2, 2); s2 += __shfl_xor(s2, 4);
    if (sub == 0) { w1pS[r] = s1; w2pS[r] = s2; }
  }
  if (tid < 128) {                              // c1 (wave of tid 0-63), c2 (64-127)
    const int lane = tid & 63;
    const float* bb = (tid < 64) ? p.p1_lin_b : p.p2_lin_b;
    const float* aw = (tid < 64) ? p.p1_att_w : p.p2_att_w;
    float s = bb[lane] * aw[lane] + bb[lane + 64] * aw[lane + 64];
#pragma unroll
    for (int m2 = 1; m2 < 64; m2 <<= 1) s += __shfl_xor(s, m2);
    if (lane == 0) wcS[tid >> 6] = s;
  }

  // ---- dense multiplicity matrix ----
  for (int e = tid; e < p.etot; e += NT) {
    int s = p.ei[e];
    if ((s >> 5) == g) {
      int d = p.ei[p.etot + e] & 31;
      atomicAdd(&Am[(s & 31) * NPGc + d], 1.f);
    }
  }
  if (tid < NPGc) atomicAdd(&Am[tid * NPGc + tid], 1.f);
  __syncthreads();

  if (tid < NPGc) {
    float s = 0.f;
    for (int i = 0; i < NPGc; ++i) s += Am[i * NPGc + tid];
    degI[tid] = s;
  }
  for (int idx = tid; idx < NPGc * FD; idx += NT) {
    int d = idx >> 7, f = idx & 127;
    float s = 0.f;
    for (int i = 0; i < NPGc; ++i) s += Am[i * NPGc + d] * sx[i * FD + f];
    bufA[idx] = s;
  }
  __syncthreads();

  mm128<NPGc, true>(bufA, p.p1_rel_w, sx, p.p1_root_w, p.p1_rel_b, xp, tid);
  __syncthreads();

  // ---- fused masked-colmax + dq dot: 32 cols x 32 lanes, 4 f's each ----
  {
    const int d = tid >> 5, lane = tid & 31;
    const int f0 = lane * 4;
    float m0 = -1e30f, m1 = -1e30f, m2v = -1e30f, m3 = -1e30f;
    for (int i = 0; i < NPGc; ++i)
      if (Am[i * NPGc + d] > 0.f) {
        const float4 v = *reinterpret_cast<const float4*>(&xp[i * FD + f0]);
        m0 = fmaxf(m0, v.x); m1 = fmaxf(m1, v.y);
        m2v = fmaxf(m2v, v.z); m3 = fmaxf(m3, v.w);
      }
    float s = m0 * w1pS[f0] + m1 * w1pS[f0 + 1] + m2v * w1pS[f0 + 2] + m3 * w1pS[f0 + 3];
#pragma unroll
    for (int m2 = 1; m2 < 32; m2 <<= 1) s += __shfl_xor(s, m2);
    if (lane == 0) dqS[d] = s + wcS[0];
  }
  // ---- dp dots: 32 rows x 32 lanes ----
  {
    const int row = tid >> 5, sub = tid & 31;
    float4 a = reinterpret_cast<const float4*>(xp + row * FD)[sub];
    float4 b = reinterpret_cast<const float4*>(p.p1_att_w + FD)[sub];
    float s = a.x * b.x + a.y * b.y + a.z * b.z + a.w * b.w;
#pragma unroll
    for (int m2 = 1; m2 < 32; m2 <<= 1) s += __shfl_xor(s, m2);
    if (sub == 0) dpS[row] = s;
  }
  __syncthreads();

  // ---- L1 masked mult-weighted softmax: 32 cols x 32 lanes ----
  {
    const int d = tid >> 5, s2 = tid & 31;
    const float ab = p.p1_att_b[0];
    const float mult = Am[s2 * NPGc + d];
    float l = dqS[d] + dpS[s2] + ab;
    l = (l > 0.f) ? l : SLOPEc * l;
    float m = (mult > 0.f) ? l : -1e30f;
#pragma unroll
    for (int m2 = 1; m2 < 32; m2 <<= 1) m = fmaxf(m, __shfl_xor(m, m2));
    float v = (mult > 0.f) ? mult * expf(l - m) : 0.f;
    float den = v;
#pragma unroll
    for (int m2 = 1; m2 < 32; m2 <<= 1) den += __shfl_xor(den, m2);
    Sm[s2 * NPGc + d] = v / den;
  }
  __syncthreads();

  for (int idx = tid; idx < NPGc * FD; idx += NT) {
    int d = idx >> 7, f = idx & 127;
    float s = 0.f;
    for (int i = 0; i < NPGc; ++i) s += Sm[i * NPGc + d] * sx[i * FD + f];
    xcb[idx] = s;
  }
  __syncthreads();

  // ---- fitness dots: 32 rows x 32 lanes ----
  {
    const int row = tid >> 5, sub = tid & 31;
    float4 xv = reinterpret_cast<const float4*>(xcb + row * FD)[sub];
    float4 wa = reinterpret_cast<const float4*>(p.p1_le1_w)[sub];
    float4 wb = reinterpret_cast<const float4*>(p.p1_le2_w)[sub];
    float4 wc = reinterpret_cast<const float4*>(p.p1_le3_w)[sub];
    float a = xv.x * wa.x + xv.y * wa.y + xv.z * wa.z + xv.w * wa.w;
    float b = xv.x * wb.x + xv.y * wb.y + xv.z * wb.z + xv.w * wb.w;
    float c = xv.x * wc.x + xv.y * wc.y + xv.z * wc.z + xv.w * wc.w;
#pragma unroll
    for (int m2 = 1; m2 < 32; m2 <<= 1) {
      a += __shfl_xor(a, m2); b += __shfl_xor(b, m2); c += __shfl_xor(c, m2);
    }
    if (sub == 0) { sA[row] = a + p.p1_le1_b[0]; sB[row] = b; sC[row] = c; }
  }
  __syncthreads();
  // ---- fitness apply: 32 cols x 32 lanes ----
  {
    const int d = tid >> 5, i = tid & 31;
    float s = Am[i * NPGc + d] * sA[i];
#pragma unroll
    for (int m2 = 1; m2 < 32; m2 <<= 1) s += __shfl_xor(s, m2);
    if (i == 0) {
      float fv = s - degI[d] * sB[d] + sC[d] + p.p1_le3_b[0];
      fitS[d] = 1.f / (1.f + expf(-fv));
    }
  }
  __syncthreads();

  if (tid < NPGc) {
    float fi = fitS[tid]; int r = 0;
    for (int j = 0; j < NPGc; ++j) { float fj = fitS[j]; r += (fj > fi) || (fj == fi && j < tid); }
    if (r < K1c) selS[r] = tid;
  }
  __syncthreads();

  for (int idx = tid; idx < K1c * FD; idx += NT) {
    int r = idx >> 7, f = idx & 127;
    int n = selS[r] & 31;
    Hh[idx] = xcb[n * FD + f] * fitS[n];
    X1[idx] = sx[n * FD + f];
  }
  __syncthreads();

  for (int idx = tid; idx < NPGc * K1c; idx += NT) {
    int i = idx >> 4, c = idx & 15;
    float s = 0.f; int sc = selS[c] & 31;
    for (int j = 0; j < NPGc; ++j) s += Am[i * NPGc + j] * Sm[j * NPGc + sc];
    Mm[idx] = s;
  }
  __syncthreads();
  for (int idx = tid; idx < K1c * K1c; idx += NT) {
    int r = idx >> 4, c = idx & 15;
    float s = 0.f; int sr = selS[r] & 31;
    for (int i = 0; i < NPGc; ++i) s += Sm[i * NPGc + sr] * Mm[i * K1c + c];
    A2m[idx] = (r == c || s != 0.f) ? 1.f : 0.f;
  }
  __syncthreads();

  // ---- GCN2 conv1 ----
  if (tid < K1c) {
    float s = 0.f;
    for (int i = 0; i < K1c; ++i) s += A2m[i * K1c + tid];
    dqS[tid] = 1.f / sqrtf(s);
  }
  __syncthreads();
  for (int idx = tid; idx < K1c * FD; idx += NT) {
    int j = idx >> 7, f = idx & 127;
    float s = 0.f;
    for (int i = 0; i < K1c; ++i) s += dqS[i] * A2m[i * K1c + j] * Hh[i * FD + f];
    Tb[idx] = 0.8f * dqS[j] * s + 0.2f * X1[idx];
  }
  __syncthreads();
  mm128<K1c, false>(Tb, p.c1w, nullptr, nullptr, nullptr, Hh, tid);
  __syncthreads();
  instnorm<K1c, true>(Hh, meanB, rstdB,
                      p.out + g * 640 + 128, p.out + g * 640 + 256, tid);
  __syncthreads();

  // ---- level 2 ----
  for (int idx = tid; idx < K1c * FD; idx += NT) {
    int j = idx >> 7, f = idx & 127;
    float s = 0.f;
    for (int i = 0; i < K1c; ++i) s += A2m[i * K1c + j] * Hh[i * FD + f];
    ag2[idx] = s;
  }
  __syncthreads();
  mm128<K1c, true>(ag2, p.p2_rel_w, Hh, p.p2_root_w, p.p2_rel_b, xp2, tid);
  __syncthreads();

  // ---- fused L2 masked-colmax + dq2 dot: 16 cols x 64 lanes, 2 f's each ----
  {
    const int j = tid >> 6, lane = tid & 63;
    const int f0 = lane * 2;
    float m0 = -1e30f, m1 = -1e30f;
    for (int i = 0; i < K1c; ++i)
      if (A2m[i * K1c + j] > 0.f) {
        const float2 v = *reinterpret_cast<const float2*>(&xp2[i * FD + f0]);
        m0 = fmaxf(m0, v.x); m1 = fmaxf(m1, v.y);
      }
    float s = m0 * w2pS[f0] + m1 * w2pS[f0 + 1];
#pragma unroll
    for (int m2 = 1; m2 < 64; m2 <<= 1) s += __shfl_xor(s, m2);
    if (lane == 0) dqS[j] = s + wcS[1];
  }
  // ---- dp2 dots: 16 rows x 64 lanes ----
  {
    const int row = tid >> 6, sub = tid & 63;
    float2 a = reinterpret_cast<const float2*>(xp2 + row * FD)[sub];
    float2 b = reinterpret_cast<const float2*>(p.p2_att_w + FD)[sub];
    float s = a.x * b.x + a.y * b.y;
#pragma unroll
    for (int m2 = 1; m2 < 64; m2 <<= 1) s += __shfl_xor(s, m2);
    if (sub == 0) dpS[row] = s;
  }
  __syncthreads();

  // ---- L2 masked softmax: 16 cols x 16 lanes ----
  if (tid < K1c * K1c) {
    const int j = tid >> 4, i = tid & 15;
    const float ab = p.p2_att_b[0];
    const float av = A2m[i * K1c + j];
    float l = dpS[i] + dqS[j] + ab;
    l = (l > 0.f) ? l : SLOPEc * l;
    float m = (av > 0.f) ? l : -1e30f;
#pragma unroll
    for (int m2 = 1; m2 < 16; m2 <<= 1) m = fmaxf(m, __shfl_xor(m, m2));
    float v = (av > 0.f) ? expf(l - m) : 0.f;
    float den = v;
#pragma unroll
    for (int m2 = 1; m2 < 16; m2 <<= 1) den += __shfl_xor(den, m2);
    S2m[i * K1c + j] = v / den;
  }
  __syncthreads();
  for (int idx = tid; idx < K1c * FD; idx += NT) {   // xc2 = S2^T h -> bufA
    int j = idx >> 7, f = idx & 127;
    float s = 0.f;
    for (int i = 0; i < K1c; ++i) s += S2m[i * K1c + j] * Hh[i * FD + f];
    xc2[idx] = s;
  }
  __syncthreads();

  // ---- L2 fitness dots: 16 rows x 64 lanes ----
  {
    const int row = tid >> 6, sub = tid & 63;
    float2 xv = reinterpret_cast<const float2*>(xc2 + row * FD)[sub];
    float2 wa = reinterpret_cast<const float2*>(p.p2_le1_w)[sub];
    float2 wb = reinterpret_cast<const float2*>(p.p2_le2_w)[sub];
    float2 wc = reinterpret_cast<const float2*>(p.p2_le3_w)[sub];
    float a = xv.x * wa.x + xv.y * wa.y;
    float b = xv.x * wb.x + xv.y * wb.y;
    float c = xv.x * wc.x + xv.y * wc.y;
#pragma unroll
    for (int m2 = 1; m2 < 64; m2 <<= 1) {
      a += __shfl_xor(a, m2); b += __shfl_xor(b, m2); c += __shfl_xor(c, m2);
    }
    if (sub == 0) { sA[row] = a + p.p2_le1_b[0]; sB[row] = b; sC[row] = c; }
  }
  __syncthreads();
  // ---- L2 fitness apply: 16 cols x 16 lanes ----
  if (tid < K1c * K1c) {
    const int j = tid >> 4, i = tid & 15;
    float av = A2m[i * K1c + j];
    float s = av * sA[i];
    float deg = av;
#pragma unroll
    for (int m2 = 1; m2 < 16; m2 <<= 1) {
      s += __shfl_xor(s, m2); deg += __shfl_xor(deg, m2);
    }
    if (i == 0) {
      float fv = s - deg * sB[j] + sC[j] + p.p2_le3_b[0];
      fitS[j] = 1.f / (1.f + expf(-fv));
    }
  }
  __syncthreads();
  if (tid < K1c) {
    float fi = fitS[tid]; int r = 0;
    for (int j = 0; j < K1c; ++j) { float fj = fitS[j]; r += (fj > fi) || (fj == fi && j < tid); }
    if (r < K2c) selS[r] = tid;
  }
  __syncthreads();
  for (int idx = tid; idx < K2c * FD; idx += NT) {
    int r = idx >> 7, f = idx & 127;
    int n = selS[r] & 15;
    h2b[idx] = xc2[n * FD + f] * fitS[n];
    x2b[idx] = X1[n * FD + f];
  }
  for (int idx = tid; idx < K1c * K2c; idx += NT) {
    int i = idx >> 3, c = idx & 7;
    float s = 0.f; int sc = selS[c] & 15;
    for (int j = 0; j < K1c; ++j) s += A2m[i * K1c + j] * S2m[j * K1c + sc];
    Mm[idx] = s;
  }
  __syncthreads();
  for (int idx = tid; idx < K2c * K2c; idx += NT) {
    int r = idx >> 3, c = idx & 7;
    float s = 0.f; int sr = selS[r] & 15;
    for (int i = 0; i < K1c; ++i) s += S2m[i * K1c + sr] * Mm[i * K2c + c];
    A3m[idx] = (r == c || s != 0.f) ? 1.f : 0.f;
  }
  __syncthreads();

  // ---- GCN2 conv2 ----
  if (tid < K2c) {
    float s = 0.f;
    for (int i = 0; i < K2c; ++i) s += A3m[i * K2c + tid];
    dqS[tid] = 1.f / sqrtf(s);
  }
  __syncthreads();
  for (int idx = tid; idx < K2c * FD; idx += NT) {
    int j = idx >> 7, f = idx & 127;
    float s = 0.f;
    for (int i = 0; i < K2c; ++i) s += dqS[i] * A3m[i * K2c + j] * h2b[i * FD + f];
    T2b[idx] = 0.8f * dqS[j] * s + 0.2f * x2b[idx];
  }
  __syncthreads();
  mm128<K2c, false>(T2b, p.c2w, nullptr, nullptr, nullptr, h2b, tid);
  __syncthreads();
  instnorm<K2c, false>(h2b, meanB, rstdB, nullptr, nullptr, tid);
  __syncthreads();

  // ---- gate dots: 8 rows x 64 lanes ----
  {
    const int row = tid >> 6, sub = tid & 63;
    if (row < K2c) {
      const float2 a = reinterpret_cast<const float2*>(h2b + row * FD)[sub];
      const float2 wv = reinterpret_cast<const float2*>(p.ggw)[sub];
      float s = a.x * wv.x + a.y * wv.y;
#pragma unroll
      for (int m2 = 1; m2 < 64; m2 <<= 1) s += __shfl_xor(s, m2);
      if (sub == 0) gateS[row] = s + p.ggb[0];
    }
  }
  __syncthreads();
  if (tid < K2c) {
    float m = -1e30f;
    for (int i = 0; i < K2c; ++i) m = fmaxf(m, gateS[i]);
    float e = expf(gateS[tid] - m);
    float ssum = 0.f;
    for (int i = 0; i < K2c; ++i) ssum += expf(gateS[i] - m);
    sA[tid] = e / ssum;
  }
  __syncthreads();
  if (tid < FD) {
    float s = 0.f;
    for (int r = 0; r < K2c; ++r) s += sA[r] * h2b[r * FD + tid];
    Mm[tid] = s;                    // pooled
  }
  __syncthreads();
  // ---- mol = pooled @ ga_nn_w + ga_nn_b : 8 k-groups x 128 fo ----
  {
    const int grp = tid >> 7, fo = tid & 127;
    float s = 0.f;
    for (int kk = 0; kk < 16; ++kk) {
      const int k = grp * 16 + kk;
      s = fmaf(Mm[k], p.gnw[k * FD + fo], s);
    }
    partial[grp * FD + fo] = s;
  }
  __syncthreads();
  if (tid < FD) {
    float s = p.gnb[tid];
#pragma unroll
    for (int grp = 0; grp < 8; ++grp) s += partial[grp * FD + tid];
    p.out[g * 640 + tid] = s;
  }
}

extern "C" void kernel_launch(void* const* d_in, const int* in_sizes, int n_in,
                              void* d_out, int out_size, void* d_ws, size_t ws_size,
                              hipStream_t stream) {
  (void)n_in; (void)d_ws; (void)ws_size; (void)out_size;
  Params p;
  p.x         = (const float*)d_in[0];
  p.p1_rel_w  = (const float*)d_in[1];
  p.p1_rel_b  = (const float*)d_in[2];
  p.p1_root_w = (const float*)d_in[3];
  p.p1_lin_w  = (const float*)d_in[4];
  p.p1_lin_b  = (const float*)d_in[5];
  p.p1_att_w  = (const float*)d_in[6];
  p.p1_att_b  = (const float*)d_in[7];
  p.p1_le1_w  = (const float*)d_in[8];
  p.p1_le1_b  = (const float*)d_in[9];
  p.p1_le2_w  = (const float*)d_in[10];
  p.p1_le3_w  = (const float*)d_in[11];
  p.p1_le3_b  = (const float*)d_in[12];
  p.p2_rel_w  = (const float*)d_in[13];
  p.p2_rel_b  = (const float*)d_in[14];
  p.p2_root_w = (const float*)d_in[15];
  p.p2_lin_w  = (const float*)d_in[16];
  p.p2_lin_b  = (const float*)d_in[17];
  p.p2_att_w  = (const float*)d_in[18];
  p.p2_att_b  = (const float*)d_in[19];
  p.p2_le1_w  = (const float*)d_in[20];
  p.p2_le1_b  = (const float*)d_in[21];
  p.p2_le2_w  = (const float*)d_in[22];
  p.p2_le3_w  = (const float*)d_in[23];
  p.p2_le3_b  = (const float*)d_in[24];
  p.c1w       = (const float*)d_in[25];
  p.c2w       = (const float*)d_in[26];
  p.ggw       = (const float*)d_in[27];
  p.ggb       = (const float*)d_in[28];
  p.gnw       = (const float*)d_in[29];
  p.gnb       = (const float*)d_in[30];
  p.ei        = (const int*)d_in[31];
  p.out       = (float*)d_out;
  p.etot      = in_sizes[31] / 2;
  mol_kernel<<<dim3(Bc), dim3(NT), 0, stream>>>(p);
}